// Round 8
// baseline (696.116 us; speedup 1.0000x reference)
//
#include <hip/hip_runtime.h>

#define B_SZ   256
#define T_SZ   512
#define EMB    128
#define HID    256
#define NCLS   32000
#define NBLK   250
#define CNT_OFF 131072   // counter offset in d_ws (h occupies [0,128K))

typedef __attribute__((ext_vector_type(8))) short short8;
typedef __attribute__((ext_vector_type(4))) float f32x4;

__device__ inline unsigned short bf16rne(float f) {
    union { float f; unsigned int u; } v; v.f = f;
    unsigned int u = v.u;
    u += 0x7FFFu + ((u >> 16) & 1u);
    return (unsigned short)(u >> 16);
}
__device__ inline unsigned pkhi(float lo, float hi) {
    union { float f; unsigned u; } a, b;
    a.f = lo; b.f = hi;
    return ((b.u + 0x8000u) & 0xFFFF0000u) | ((a.u + 0x8000u) >> 16);
}

// ---------------------------------------------------------------------------
// Fused kernel. 250 blocks x 512 thr, 129 KB dynamic LDS -> 1 block/CU ->
// all blocks co-resident -> manual grid barrier is safe.
//
// Phase A (waves 0-3): LSTM last-step h for row(s) of this block (layer-0
//   state never updates; layer-1 scan discarded; only t=T-1 matters).
//   Clean per-wave vmcnt -> no interference with W stream.
// Phase A' (waves 4-7): stream this block's 128-row W slice (128 KB f32)
//   into LDS via global_load_lds, source pre-swizzled XOR(row&7) (rule 21).
//   Starts at t~0; phase A hides under it.
// Grid barrier: counter in d_ws (memset to 0 each call), release fence
//   (buffer_wbl2: h dirty lines -> LLC) + agent atomic add; spin by t0 with
//   agent acquire loads + acquire fence (buffer_inv: stale L1/L2 dropped).
// Phase B (all 8 waves): W LDS->regs (same XOR, 2-way free), cvt bf16;
//   barrier; h (frag-major, linear, conflict-free) overwrites W region via
//   global_load_lds; vmcnt(0); 128 MFMA; bias; f32x4 stores.
// ---------------------------------------------------------------------------
__global__ __launch_bounds__(512)
void fused_lstm_logits(const int* __restrict__ X, const float* __restrict__ C_table,
                       const float* __restrict__ U_i, const float* __restrict__ b_i,
                       const float* __restrict__ U_c, const float* __restrict__ b_c,
                       const float* __restrict__ U_o, const float* __restrict__ b_o,
                       const float* __restrict__ Ww, const float* __restrict__ b_out,
                       unsigned short* __restrict__ hws, unsigned int* __restrict__ cnt,
                       float* __restrict__ out) {
    extern __shared__ char smem[];
    float*          Wlds = (float*)smem;                  // [0,128K) f32 W
    unsigned short* Hs   = (unsigned short*)smem;         // reused for h
    float*          eL   = (float*)(smem + 131072);       // 2 x 128 f32

    const int t    = threadIdx.x;
    const int bid  = blockIdx.x;
    const int wid  = t >> 6;
    const int lane = t & 63;
    const int l15  = lane & 15;
    const int lq   = lane >> 4;
    const int nbase = bid * 128 + wid * 16;

    f32x4 bv = *reinterpret_cast<const f32x4*>(b_out + nbase + lq * 4);

    if (t >= 256) {
        // ---- waves 4-7: issue W stream IMMEDIATELY (own vmcnt counter) ----
        const int w4 = wid - 4;                            // 0..3
        #pragma unroll
        for (int i = 0; i < 32; ++i) {
            const int r = w4 * 32 + i;                     // 0..127, wave-uniform
            const float* src = Ww + (size_t)(bid * 128 + r) * HID
                                  + ((lane ^ (r & 7)) << 2);
            __builtin_amdgcn_global_load_lds(
                (const __attribute__((address_space(1))) unsigned int*)src,
                (__attribute__((address_space(3))) unsigned int*)(Wlds + r * HID),
                16, 0, 0);
        }
    } else {
        // ---- waves 0-3: stage E row(s) ----
        if (t < 128) {
            const int tok = X[(size_t)bid * T_SZ + (T_SZ - 1)];
            eL[t] = C_table[(size_t)tok * EMB + t];
        } else if (bid < 6) {
            const int tok = X[(size_t)(NBLK + bid) * T_SZ + (T_SZ - 1)];
            eL[t] = C_table[(size_t)tok * EMB + (t - 128)];
        }
        asm volatile("s_waitcnt vmcnt(0) lgkmcnt(0)" ::: "memory");
    }
    __builtin_amdgcn_s_barrier();            // B1: E ready
    __builtin_amdgcn_sched_barrier(0);

    if (t < 256) {
        // ---- phase A: LSTM gates for row(s) m ----
        const int k = t;
        const int nrows = (bid < 6) ? 2 : 1;
        for (int rr = 0; rr < nrows; ++rr) {
            const int m = rr ? (NBLK + bid) : bid;
            const float* e = eL + rr * EMB;
            float ai = 0.f, ac = 0.f, ao = 0.f;
            #pragma unroll
            for (int c = 0; c < 4; ++c) {
                float ui[32], uc[32], uo[32];
                #pragma unroll
                for (int j = 0; j < 32; ++j) {
                    const int ee = c * 32 + j;
                    ui[j] = U_i[ee * HID + k];
                    uc[j] = U_c[ee * HID + k];
                    uo[j] = U_o[ee * HID + k];
                }
                #pragma unroll
                for (int j = 0; j < 32; ++j)
                    asm volatile("" : "+v"(ui[j]), "+v"(uc[j]), "+v"(uo[j]));
                #pragma unroll
                for (int j = 0; j < 32; ++j) {
                    const float ev = e[c * 32 + j];
                    ai += ev * ui[j]; ac += ev * uc[j]; ao += ev * uo[j];
                }
            }
            const float i0 = 1.f / (1.f + expf(-(ai + b_i[k])));
            const float g0 = tanhf(ac + b_c[k]);
            const float o0 = 1.f / (1.f + expf(-(ao + b_o[k])));
            const unsigned short hv = bf16rne(o0 * tanhf(i0 * g0));
            const int frag = (m >> 4) * 8 + (k >> 5);
            const int li   = ((k >> 3) & 3) * 16 + (m & 15);
            hws[frag * 512 + li * 8 + (k & 7)] = hv;
        }
        asm volatile("s_waitcnt vmcnt(0)" ::: "memory");   // h stores at L2
    } else {
        asm volatile("s_waitcnt vmcnt(0)" ::: "memory");   // W fully in LDS
    }
    __builtin_amdgcn_s_barrier();            // B2: block's h + W-LDS done
    __builtin_amdgcn_sched_barrier(0);

    // ---- grid barrier ----
    if (t == 0) {
        __threadfence();                                    // release: wbl2
        __hip_atomic_fetch_add(cnt, 1u, __ATOMIC_RELEASE, __HIP_MEMORY_SCOPE_AGENT);
        unsigned v; long g = 0;
        do {
            v = __hip_atomic_load(cnt, __ATOMIC_ACQUIRE, __HIP_MEMORY_SCOPE_AGENT);
        } while (v < (unsigned)NBLK && ++g < (1L << 20));
        __threadfence();                                    // acquire: inv
    }
    __builtin_amdgcn_s_barrier();            // B3: all h visible
    __builtin_amdgcn_sched_barrier(0);

    // ---- W stripe LDS -> regs, cvt bf16 ----
    short8 aw[8];
    {
        const int R  = wid * 16 + l15;
        const int sw = R & 7;
        const float* rp = Wlds + R * HID;
        #pragma unroll
        for (int ks = 0; ks < 8; ++ks) {
            const int j0 = ks * 8 + lq * 2;
            f32x4 w0 = *reinterpret_cast<const f32x4*>(rp + ((j0 ^ sw) << 2));
            f32x4 w1 = *reinterpret_cast<const f32x4*>(rp + (((j0 + 1) ^ sw) << 2));
            union { short8 s; unsigned u[4]; } p;
            p.u[0] = pkhi(w0[0], w0[1]);
            p.u[1] = pkhi(w0[2], w0[3]);
            p.u[2] = pkhi(w1[0], w1[1]);
            p.u[3] = pkhi(w1[2], w1[3]);
            aw[ks] = p.s;
        }
    }
    asm volatile("s_waitcnt lgkmcnt(0)" ::: "memory");
    __builtin_amdgcn_s_barrier();            // B4: W reads done, LDS reusable
    __builtin_amdgcn_sched_barrier(0);

    // ---- stage h (frag-major, linear) into LDS ----
    #pragma unroll
    for (int j = 0; j < 16; ++j) {
        const unsigned short* src = hws + (wid * 16 + j) * 512 + lane * 8;
        __builtin_amdgcn_global_load_lds(
            (const __attribute__((address_space(1))) unsigned int*)src,
            (__attribute__((address_space(3))) unsigned int*)(Hs + (wid * 16 + j) * 512),
            16, 0, 0);
    }
    asm volatile("s_waitcnt vmcnt(0)" ::: "memory");
    __builtin_amdgcn_s_barrier();            // B5: h in LDS
    __builtin_amdgcn_sched_barrier(0);

    // ---- MFMA: 8 ks x 16 mf, B-frags conflict-free from LDS ----
    const unsigned short* hbase = Hs + lane * 8;
    f32x4 acc[16] = {};
    #pragma unroll
    for (int ks = 0; ks < 8; ++ks) {
        #pragma unroll
        for (int mf = 0; mf < 16; ++mf) {
            short8 bh = *reinterpret_cast<const short8*>(hbase + (mf * 8 + ks) * 512);
            acc[mf] = __builtin_amdgcn_mfma_f32_16x16x32_bf16(aw[ks], bh, acc[mf], 0, 0, 0);
        }
    }

    // ---- epilogue: D[n][m] col=l15=m, rows=lq*4+reg -> f32x4 stores ----
    #pragma unroll
    for (int mf = 0; mf < 16; ++mf) {
        f32x4 o = acc[mf] + bv;
        *reinterpret_cast<f32x4*>(
            out + (size_t)(mf * 16 + l15) * NCLS + nbase + lq * 4) = o;
    }
}

// ---------------------------------------------------------------------------
extern "C" void kernel_launch(void* const* d_in, const int* in_sizes, int n_in,
                              void* d_out, int out_size, void* d_ws, size_t ws_size,
                              hipStream_t stream) {
    const int*   X       = (const int*)  d_in[0];
    const float* C_table = (const float*)d_in[1];
    const float* U_i     = (const float*)d_in[2];
    const float* b_i     = (const float*)d_in[4];
    const float* U_c     = (const float*)d_in[8];
    const float* b_c     = (const float*)d_in[10];
    const float* U_o     = (const float*)d_in[11];
    const float* b_o     = (const float*)d_in[13];
    const float* W_w     = (const float*)d_in[26];
    const float* b_out   = (const float*)d_in[27];
    float* out = (float*)d_out;

    unsigned short* hws = (unsigned short*)d_ws;                      // 128 KB
    unsigned int*   cnt = (unsigned int*)((char*)d_ws + CNT_OFF);

    const size_t smem = 131072 + 1024;   // W/h region + E rows
    hipFuncSetAttribute((const void*)fused_lstm_logits,
                        hipFuncAttributeMaxDynamicSharedMemorySize, (int)smem);
    hipMemsetAsync(cnt, 0, 4, stream);   // zero grid-barrier counter each call

    fused_lstm_logits<<<NBLK, 512, smem, stream>>>(
        X, C_table, U_i, b_i, U_c, b_c, U_o, b_o, W_w, b_out, hws, cnt, out);
}

// Round 9
// 667.027 us; speedup vs baseline: 1.0436x; 1.0436x over previous
//
#include <hip/hip_runtime.h>

#define B_SZ   256
#define T_SZ   512
#define EMB    128
#define HID    256
#define NCLS   32000
#define NBLK   250
#define CNT_OFF 131072   // counter offset in d_ws (h occupies [0,128K))

typedef __attribute__((ext_vector_type(8))) short short8;
typedef __attribute__((ext_vector_type(4))) float f32x4;

__device__ inline unsigned short bf16rne(float f) {
    union { float f; unsigned int u; } v; v.f = f;
    unsigned int u = v.u;
    u += 0x7FFFu + ((u >> 16) & 1u);
    return (unsigned short)(u >> 16);
}
__device__ inline unsigned pkhi(float lo, float hi) {
    union { float f; unsigned u; } a, b;
    a.f = lo; b.f = hi;
    return ((b.u + 0x8000u) & 0xFFFF0000u) | ((a.u + 0x8000u) >> 16);
}

// ---------------------------------------------------------------------------
// Fused kernel, repaired from R8. 250 blocks x 512 thr.
// STATIC __shared__ (129 KB -> compiler knows 1 block/CU) and
// __launch_bounds__(512,2) (8 waves/CU -> VGPR cap 256): kills the R8
// spill disaster (VGPR=128, 300 MB scratch traffic, 720 us).
//
// Phase A (waves 0-3): LSTM last-step h for this block's row(s) (layer-0
//   state never updates; layer-1 scan discarded; only t=T-1 matters).
// Phase A' (waves 4-7): stream the block's 128-row W slice (128 KB f32)
//   into LDS via global_load_lds, source pre-swizzled XOR(row&7) (rule 21).
//   Starts at t~0; phase A hides under it; separate per-wave vmcnt.
// Grid barrier (counter in d_ws, memset each call; release/acquire fences
//   for cross-XCD visibility of h). Validated correct in R8.
// Phase B (all 8 waves): W LDS->regs (same XOR), cvt bf16; barrier;
//   h (frag-major, linear, conflict-free) overwrites W region via
//   global_load_lds; vmcnt(0); 128 MFMA; bias; f32x4 stores.
// ---------------------------------------------------------------------------
__global__ __launch_bounds__(512, 2)
void fused_lstm_logits(const int* __restrict__ X, const float* __restrict__ C_table,
                       const float* __restrict__ U_i, const float* __restrict__ b_i,
                       const float* __restrict__ U_c, const float* __restrict__ b_c,
                       const float* __restrict__ U_o, const float* __restrict__ b_o,
                       const float* __restrict__ Ww, const float* __restrict__ b_out,
                       unsigned short* __restrict__ hws, unsigned int* __restrict__ cnt,
                       float* __restrict__ out) {
    __shared__ float Wlds[32768];            // 128 KB: W f32, later reused as h
    __shared__ float eL[2 * EMB];            // E rows (1 KB)
    unsigned short* Hs = (unsigned short*)Wlds;

    const int t    = threadIdx.x;
    const int bid  = blockIdx.x;
    const int wid  = t >> 6;
    const int lane = t & 63;
    const int l15  = lane & 15;
    const int lq   = lane >> 4;
    const int nbase = bid * 128 + wid * 16;

    f32x4 bv = *reinterpret_cast<const f32x4*>(b_out + nbase + lq * 4);

    if (t >= 256) {
        // ---- waves 4-7: issue W stream IMMEDIATELY (own vmcnt counter) ----
        const int w4 = wid - 4;                            // 0..3
        #pragma unroll
        for (int i = 0; i < 32; ++i) {
            const int r = w4 * 32 + i;                     // 0..127, wave-uniform
            const float* src = Ww + (size_t)(bid * 128 + r) * HID
                                  + ((lane ^ (r & 7)) << 2);
            __builtin_amdgcn_global_load_lds(
                (const __attribute__((address_space(1))) unsigned int*)src,
                (__attribute__((address_space(3))) unsigned int*)(Wlds + r * HID),
                16, 0, 0);
        }
    } else {
        // ---- waves 0-3: stage E row(s) ----
        if (t < 128) {
            const int tok = X[(size_t)bid * T_SZ + (T_SZ - 1)];
            eL[t] = C_table[(size_t)tok * EMB + t];
        } else if (bid < 6) {
            const int tok = X[(size_t)(NBLK + bid) * T_SZ + (T_SZ - 1)];
            eL[t] = C_table[(size_t)tok * EMB + (t - 128)];
        }
        asm volatile("s_waitcnt vmcnt(0) lgkmcnt(0)" ::: "memory");
    }
    __builtin_amdgcn_s_barrier();            // B1: E ready
    __builtin_amdgcn_sched_barrier(0);

    if (t < 256) {
        // ---- phase A: LSTM gates for this block's row(s) ----
        const int k = t;
        const int nrows = (bid < 6) ? 2 : 1;
        for (int rr = 0; rr < nrows; ++rr) {
            const int m = rr ? (NBLK + bid) : bid;
            const float* e = eL + rr * EMB;
            float ai = 0.f, ac = 0.f, ao = 0.f;
            #pragma unroll
            for (int c = 0; c < 4; ++c) {
                float ui[32], uc[32], uo[32];
                #pragma unroll
                for (int j = 0; j < 32; ++j) {
                    const int ee = c * 32 + j;
                    ui[j] = U_i[ee * HID + k];
                    uc[j] = U_c[ee * HID + k];
                    uo[j] = U_o[ee * HID + k];
                }
                #pragma unroll
                for (int j = 0; j < 32; ++j)
                    asm volatile("" : "+v"(ui[j]), "+v"(uc[j]), "+v"(uo[j]));
                #pragma unroll
                for (int j = 0; j < 32; ++j) {
                    const float ev = e[c * 32 + j];
                    ai += ev * ui[j]; ac += ev * uc[j]; ao += ev * uo[j];
                }
            }
            const float i0 = 1.f / (1.f + expf(-(ai + b_i[k])));
            const float g0 = tanhf(ac + b_c[k]);
            const float o0 = 1.f / (1.f + expf(-(ao + b_o[k])));
            const unsigned short hv = bf16rne(o0 * tanhf(i0 * g0));
            const int frag = (m >> 4) * 8 + (k >> 5);
            const int li   = ((k >> 3) & 3) * 16 + (m & 15);
            hws[frag * 512 + li * 8 + (k & 7)] = hv;
        }
        asm volatile("s_waitcnt vmcnt(0)" ::: "memory");   // h stores issued
    } else {
        asm volatile("s_waitcnt vmcnt(0)" ::: "memory");   // W fully in LDS
    }
    __builtin_amdgcn_s_barrier();            // B2: block's h + W-LDS done
    __builtin_amdgcn_sched_barrier(0);

    // ---- grid barrier (all 250 blocks co-resident: 1 block/CU) ----
    if (t == 0) {
        __threadfence();                                    // release
        __hip_atomic_fetch_add(cnt, 1u, __ATOMIC_RELEASE, __HIP_MEMORY_SCOPE_AGENT);
        unsigned v; long g = 0;
        do {
            v = __hip_atomic_load(cnt, __ATOMIC_ACQUIRE, __HIP_MEMORY_SCOPE_AGENT);
        } while (v < (unsigned)NBLK && ++g < (1L << 20));
        __threadfence();                                    // acquire
    }
    __builtin_amdgcn_s_barrier();            // B3: all h visible
    __builtin_amdgcn_sched_barrier(0);

    // ---- W stripe LDS -> regs, cvt bf16 ----
    short8 aw[8];
    {
        const int R  = wid * 16 + l15;
        const int sw = R & 7;
        const float* rp = Wlds + R * HID;
        #pragma unroll
        for (int ks = 0; ks < 8; ++ks) {
            const int j0 = ks * 8 + lq * 2;
            f32x4 w0 = *reinterpret_cast<const f32x4*>(rp + ((j0 ^ sw) << 2));
            f32x4 w1 = *reinterpret_cast<const f32x4*>(rp + (((j0 + 1) ^ sw) << 2));
            union { short8 s; unsigned u[4]; } p;
            p.u[0] = pkhi(w0[0], w0[1]);
            p.u[1] = pkhi(w0[2], w0[3]);
            p.u[2] = pkhi(w1[0], w1[1]);
            p.u[3] = pkhi(w1[2], w1[3]);
            aw[ks] = p.s;
        }
    }
    asm volatile("s_waitcnt lgkmcnt(0)" ::: "memory");
    __builtin_amdgcn_s_barrier();            // B4: W reads done, LDS reusable
    __builtin_amdgcn_sched_barrier(0);

    // ---- stage h (frag-major, linear, conflict-free) into LDS ----
    #pragma unroll
    for (int j = 0; j < 16; ++j) {
        const unsigned short* src = hws + (wid * 16 + j) * 512 + lane * 8;
        __builtin_amdgcn_global_load_lds(
            (const __attribute__((address_space(1))) unsigned int*)src,
            (__attribute__((address_space(3))) unsigned int*)(Hs + (wid * 16 + j) * 512),
            16, 0, 0);
    }
    asm volatile("s_waitcnt vmcnt(0)" ::: "memory");
    __builtin_amdgcn_s_barrier();            // B5: h in LDS
    __builtin_amdgcn_sched_barrier(0);

    // ---- MFMA: 8 ks x 16 mf, B-frags conflict-free from LDS ----
    const unsigned short* hbase = Hs + lane * 8;
    f32x4 acc[16] = {};
    #pragma unroll
    for (int ks = 0; ks < 8; ++ks) {
        #pragma unroll
        for (int mf = 0; mf < 16; ++mf) {
            short8 bh = *reinterpret_cast<const short8*>(hbase + (mf * 8 + ks) * 512);
            acc[mf] = __builtin_amdgcn_mfma_f32_16x16x32_bf16(aw[ks], bh, acc[mf], 0, 0, 0);
        }
    }

    // ---- epilogue: D[n][m] col=l15=m, rows=lq*4+reg -> f32x4 stores ----
    #pragma unroll
    for (int mf = 0; mf < 16; ++mf) {
        f32x4 o = acc[mf] + bv;
        *reinterpret_cast<f32x4*>(
            out + (size_t)(mf * 16 + l15) * NCLS + nbase + lq * 4) = o;
    }
}

// ---------------------------------------------------------------------------
extern "C" void kernel_launch(void* const* d_in, const int* in_sizes, int n_in,
                              void* d_out, int out_size, void* d_ws, size_t ws_size,
                              hipStream_t stream) {
    const int*   X       = (const int*)  d_in[0];
    const float* C_table = (const float*)d_in[1];
    const float* U_i     = (const float*)d_in[2];
    const float* b_i     = (const float*)d_in[4];
    const float* U_c     = (const float*)d_in[8];
    const float* b_c     = (const float*)d_in[10];
    const float* U_o     = (const float*)d_in[11];
    const float* b_o     = (const float*)d_in[13];
    const float* W_w     = (const float*)d_in[26];
    const float* b_out   = (const float*)d_in[27];
    float* out = (float*)d_out;

    unsigned short* hws = (unsigned short*)d_ws;                      // 128 KB
    unsigned int*   cnt = (unsigned int*)((char*)d_ws + CNT_OFF);

    hipMemsetAsync(cnt, 0, 4, stream);   // zero grid-barrier counter each call

    fused_lstm_logits<<<NBLK, 512, 0, stream>>>(
        X, C_table, U_i, b_i, U_c, b_c, U_o, b_o, W_w, b_out, hws, cnt, out);
}

// Round 10
// 347.864 us; speedup vs baseline: 2.0011x; 1.9175x over previous
//
#include <hip/hip_runtime.h>

#define B_SZ   256
#define T_SZ   512
#define EMB    128
#define HID    256
#define NCLS   32000
#define NBLK   250
#define CNT_OFF 131072   // counter offset in d_ws (h occupies [0,128K))

typedef __attribute__((ext_vector_type(8))) short short8;
typedef __attribute__((ext_vector_type(4))) float f32x4;

__device__ inline unsigned short bf16rne(float f) {
    union { float f; unsigned int u; } v; v.f = f;
    unsigned int u = v.u;
    u += 0x7FFFu + ((u >> 16) & 1u);
    return (unsigned short)(u >> 16);
}
__device__ inline unsigned pkhi(float lo, float hi) {
    union { float f; unsigned u; } a, b;
    a.f = lo; b.f = hi;
    return ((b.u + 0x8000u) & 0xFFFF0000u) | ((a.u + 0x8000u) >> 16);
}

// ---------------------------------------------------------------------------
// Fused kernel. 250 blocks x 512 thr, static 129 KB LDS -> 1 block/CU ->
// all 250 blocks co-resident (R9 occupancy 23.8% == 250*8/8192 confirmed).
//
// R10 change vs R9 (single variable): the grid-barrier spin.
// R8/R9 spun on ACQUIRE agent loads -> per-iteration L2 invalidates from
// 250 spinners thrashed every XCD's L2 (FETCH 125MB, WRITE 240MB, 720us,
// all-idle counters). Now: one release fence + RELAXED add; spin on
// RELAXED loads with s_sleep backoff; ONE acquire fence after exit.
// Same memory-model guarantees, no per-iteration cache maintenance.
//
// Phase A (waves 0-3): LSTM last-step h (layer-0 state never updates;
//   layer-1 scan discarded; only t=T-1 matters) -> frag-major hws.
// Phase A' (waves 4-7): stream block's 128-row W slice (128 KB f32) into
//   LDS via global_load_lds, source pre-swizzled XOR(row&7) (rule 21).
// Grid barrier. Then phase B (all 8 waves): W LDS->regs (same XOR), cvt
//   bf16; barrier; h (frag-major, linear, conflict-free) overwrites W
//   region via global_load_lds; vmcnt(0); 128 MFMA; bias; f32x4 stores.
// ---------------------------------------------------------------------------
__global__ __launch_bounds__(512, 2)
void fused_lstm_logits(const int* __restrict__ X, const float* __restrict__ C_table,
                       const float* __restrict__ U_i, const float* __restrict__ b_i,
                       const float* __restrict__ U_c, const float* __restrict__ b_c,
                       const float* __restrict__ U_o, const float* __restrict__ b_o,
                       const float* __restrict__ Ww, const float* __restrict__ b_out,
                       unsigned short* __restrict__ hws, unsigned int* __restrict__ cnt,
                       float* __restrict__ out) {
    __shared__ float Wlds[32768];            // 128 KB: W f32, later reused as h
    __shared__ float eL[2 * EMB];            // E rows (1 KB)
    unsigned short* Hs = (unsigned short*)Wlds;

    const int t    = threadIdx.x;
    const int bid  = blockIdx.x;
    const int wid  = t >> 6;
    const int lane = t & 63;
    const int l15  = lane & 15;
    const int lq   = lane >> 4;
    const int nbase = bid * 128 + wid * 16;

    f32x4 bv = *reinterpret_cast<const f32x4*>(b_out + nbase + lq * 4);

    if (t >= 256) {
        // ---- waves 4-7: issue W stream IMMEDIATELY (own vmcnt counter) ----
        const int w4 = wid - 4;                            // 0..3
        #pragma unroll
        for (int i = 0; i < 32; ++i) {
            const int r = w4 * 32 + i;                     // 0..127, wave-uniform
            const float* src = Ww + (size_t)(bid * 128 + r) * HID
                                  + ((lane ^ (r & 7)) << 2);
            __builtin_amdgcn_global_load_lds(
                (const __attribute__((address_space(1))) unsigned int*)src,
                (__attribute__((address_space(3))) unsigned int*)(Wlds + r * HID),
                16, 0, 0);
        }
    } else {
        // ---- waves 0-3: stage E row(s) ----
        if (t < 128) {
            const int tok = X[(size_t)bid * T_SZ + (T_SZ - 1)];
            eL[t] = C_table[(size_t)tok * EMB + t];
        } else if (bid < 6) {
            const int tok = X[(size_t)(NBLK + bid) * T_SZ + (T_SZ - 1)];
            eL[t] = C_table[(size_t)tok * EMB + (t - 128)];
        }
        asm volatile("s_waitcnt vmcnt(0) lgkmcnt(0)" ::: "memory");
    }
    __builtin_amdgcn_s_barrier();            // B1: E ready
    __builtin_amdgcn_sched_barrier(0);

    if (t < 256) {
        // ---- phase A: LSTM gates for this block's row(s) ----
        const int k = t;
        const int nrows = (bid < 6) ? 2 : 1;
        for (int rr = 0; rr < nrows; ++rr) {
            const int m = rr ? (NBLK + bid) : bid;
            const float* e = eL + rr * EMB;
            float ai = 0.f, ac = 0.f, ao = 0.f;
            #pragma unroll
            for (int c = 0; c < 4; ++c) {
                float ui[32], uc[32], uo[32];
                #pragma unroll
                for (int j = 0; j < 32; ++j) {
                    const int ee = c * 32 + j;
                    ui[j] = U_i[ee * HID + k];
                    uc[j] = U_c[ee * HID + k];
                    uo[j] = U_o[ee * HID + k];
                }
                #pragma unroll
                for (int j = 0; j < 32; ++j)
                    asm volatile("" : "+v"(ui[j]), "+v"(uc[j]), "+v"(uo[j]));
                #pragma unroll
                for (int j = 0; j < 32; ++j) {
                    const float ev = e[c * 32 + j];
                    ai += ev * ui[j]; ac += ev * uc[j]; ao += ev * uo[j];
                }
            }
            const float i0 = 1.f / (1.f + expf(-(ai + b_i[k])));
            const float g0 = tanhf(ac + b_c[k]);
            const float o0 = 1.f / (1.f + expf(-(ao + b_o[k])));
            const unsigned short hv = bf16rne(o0 * tanhf(i0 * g0));
            const int frag = (m >> 4) * 8 + (k >> 5);
            const int li   = ((k >> 3) & 3) * 16 + (m & 15);
            hws[frag * 512 + li * 8 + (k & 7)] = hv;
        }
        asm volatile("s_waitcnt vmcnt(0)" ::: "memory");   // h stores issued
    } else {
        asm volatile("s_waitcnt vmcnt(0)" ::: "memory");   // W fully in LDS
    }
    __builtin_amdgcn_s_barrier();            // B2: block's h + W-LDS done
    __builtin_amdgcn_sched_barrier(0);

    // ---- grid barrier: relaxed spin + single fences (R10 fix) ----
    if (t == 0) {
        __threadfence();                                    // release: h -> LLC
        __hip_atomic_fetch_add(cnt, 1u, __ATOMIC_RELAXED,
                               __HIP_MEMORY_SCOPE_AGENT);
        long g = 0;
        while (__hip_atomic_load(cnt, __ATOMIC_RELAXED,
                                 __HIP_MEMORY_SCOPE_AGENT) < (unsigned)NBLK
               && ++g < (1L << 16)) {
            __builtin_amdgcn_s_sleep(2);                    // ~128 cy backoff
        }
        __threadfence();                                    // acquire: inv once
    }
    __builtin_amdgcn_s_barrier();            // B3: all h visible
    __builtin_amdgcn_sched_barrier(0);

    // ---- W stripe LDS -> regs, cvt bf16 ----
    short8 aw[8];
    {
        const int R  = wid * 16 + l15;
        const int sw = R & 7;
        const float* rp = Wlds + R * HID;
        #pragma unroll
        for (int ks = 0; ks < 8; ++ks) {
            const int j0 = ks * 8 + lq * 2;
            f32x4 w0 = *reinterpret_cast<const f32x4*>(rp + ((j0 ^ sw) << 2));
            f32x4 w1 = *reinterpret_cast<const f32x4*>(rp + (((j0 + 1) ^ sw) << 2));
            union { short8 s; unsigned u[4]; } p;
            p.u[0] = pkhi(w0[0], w0[1]);
            p.u[1] = pkhi(w0[2], w0[3]);
            p.u[2] = pkhi(w1[0], w1[1]);
            p.u[3] = pkhi(w1[2], w1[3]);
            aw[ks] = p.s;
        }
    }
    asm volatile("s_waitcnt lgkmcnt(0)" ::: "memory");
    __builtin_amdgcn_s_barrier();            // B4: W reads done, LDS reusable
    __builtin_amdgcn_sched_barrier(0);

    // ---- stage h (frag-major, linear, conflict-free) into LDS ----
    #pragma unroll
    for (int j = 0; j < 16; ++j) {
        const unsigned short* src = hws + (wid * 16 + j) * 512 + lane * 8;
        __builtin_amdgcn_global_load_lds(
            (const __attribute__((address_space(1))) unsigned int*)src,
            (__attribute__((address_space(3))) unsigned int*)(Hs + (wid * 16 + j) * 512),
            16, 0, 0);
    }
    asm volatile("s_waitcnt vmcnt(0)" ::: "memory");
    __builtin_amdgcn_s_barrier();            // B5: h in LDS
    __builtin_amdgcn_sched_barrier(0);

    // ---- MFMA: 8 ks x 16 mf, B-frags conflict-free from LDS ----
    const unsigned short* hbase = Hs + lane * 8;
    f32x4 acc[16] = {};
    #pragma unroll
    for (int ks = 0; ks < 8; ++ks) {
        #pragma unroll
        for (int mf = 0; mf < 16; ++mf) {
            short8 bh = *reinterpret_cast<const short8*>(hbase + (mf * 8 + ks) * 512);
            acc[mf] = __builtin_amdgcn_mfma_f32_16x16x32_bf16(aw[ks], bh, acc[mf], 0, 0, 0);
        }
    }

    // ---- epilogue: D[n][m] col=l15=m, rows=lq*4+reg -> f32x4 stores ----
    #pragma unroll
    for (int mf = 0; mf < 16; ++mf) {
        f32x4 o = acc[mf] + bv;
        *reinterpret_cast<f32x4*>(
            out + (size_t)(mf * 16 + l15) * NCLS + nbase + lq * 4) = o;
    }
}

// ---------------------------------------------------------------------------
extern "C" void kernel_launch(void* const* d_in, const int* in_sizes, int n_in,
                              void* d_out, int out_size, void* d_ws, size_t ws_size,
                              hipStream_t stream) {
    const int*   X       = (const int*)  d_in[0];
    const float* C_table = (const float*)d_in[1];
    const float* U_i     = (const float*)d_in[2];
    const float* b_i     = (const float*)d_in[4];
    const float* U_c     = (const float*)d_in[8];
    const float* b_c     = (const float*)d_in[10];
    const float* U_o     = (const float*)d_in[11];
    const float* b_o     = (const float*)d_in[13];
    const float* W_w     = (const float*)d_in[26];
    const float* b_out   = (const float*)d_in[27];
    float* out = (float*)d_out;

    unsigned short* hws = (unsigned short*)d_ws;                      // 128 KB
    unsigned int*   cnt = (unsigned int*)((char*)d_ws + CNT_OFF);

    hipMemsetAsync(cnt, 0, 4, stream);   // zero grid-barrier counter each call

    fused_lstm_logits<<<NBLK, 512, 0, stream>>>(
        X, C_table, U_i, b_i, U_c, b_c, U_o, b_o, W_w, b_out, hws, cnt, out);
}

// Round 11
// 32.376 us; speedup vs baseline: 21.5011x; 10.7445x over previous
//
#include <hip/hip_runtime.h>

#define B_SZ   256
#define T_SZ   512
#define EMB    128
#define HID    256
#define NCLS   32000

typedef __attribute__((ext_vector_type(8))) short short8;
typedef __attribute__((ext_vector_type(4))) float f32x4;

__device__ inline unsigned short bf16rne(float f) {
    union { float f; unsigned int u; } v; v.f = f;
    unsigned int u = v.u;
    u += 0x7FFFu + ((u >> 16) & 1u);
    return (unsigned short)(u >> 16);
}
__device__ inline unsigned pkhi(float lo, float hi) {
    union { float f; unsigned u; } a, b;
    a.f = lo; b.f = hi;
    return ((b.u + 0x8000u) & 0xFFFF0000u) | ((a.u + 0x8000u) >> 16);
}

// ---------------------------------------------------------------------------
// h is stored FRAG-MAJOR in d_ws: element (m,k) at
//   frag = (m>>4)*8 + (k>>5); lane = ((k>>3)&3)*16 + (m&15);
//   idx  = frag*512 + lane*8 + (k&7)
// so each B-fragment is a contiguous lane-linear 1 KB block: LDS staging is
// linear (no swizzle, rule 21) and ds_read_b128 is conflict-free (R7-proven).
// ---------------------------------------------------------------------------

// ---------------------------------------------------------------------------
// Kernel 1: h_last[b][k] for t = T-1 only (layer-0 state never updates;
// layer-1 scan discarded). VERBATIM from R7 (passed, 30.1 us total).
// ---------------------------------------------------------------------------
__global__ __launch_bounds__(256)
void lstm_h_last(const int* __restrict__ X, const float* __restrict__ C_table,
                 const float* __restrict__ U_i, const float* __restrict__ b_i,
                 const float* __restrict__ U_c, const float* __restrict__ b_c,
                 const float* __restrict__ U_o, const float* __restrict__ b_o,
                 unsigned short* __restrict__ hws) {
    __shared__ float e[EMB];
    const int m = blockIdx.x;
    const int k = threadIdx.x;

    const int token = X[(size_t)m * T_SZ + (T_SZ - 1)];
    if (k < EMB) e[k] = C_table[(size_t)token * EMB + k];
    __syncthreads();

    float ai = 0.f, ac = 0.f, ao = 0.f;
    #pragma unroll
    for (int c = 0; c < 4; ++c) {
        float ui[32], uc[32], uo[32];
        #pragma unroll
        for (int j = 0; j < 32; ++j) {
            const int ee = c * 32 + j;
            ui[j] = U_i[ee * HID + k];
            uc[j] = U_c[ee * HID + k];
            uo[j] = U_o[ee * HID + k];
        }
        #pragma unroll
        for (int j = 0; j < 32; ++j)
            asm volatile("" : "+v"(ui[j]), "+v"(uc[j]), "+v"(uo[j]));
        #pragma unroll
        for (int j = 0; j < 32; ++j) {
            const float ev = e[c * 32 + j];
            ai += ev * ui[j]; ac += ev * uc[j]; ao += ev * uo[j];
        }
    }

    const float i0 = 1.f / (1.f + expf(-(ai + b_i[k])));
    const float g0 = tanhf(ac + b_c[k]);
    const float o0 = 1.f / (1.f + expf(-(ao + b_o[k])));
    const unsigned short hv = bf16rne(o0 * tanhf(i0 * g0));

    const int frag = (m >> 4) * 8 + (k >> 5);
    const int li   = ((k >> 3) & 3) * 16 + (m & 15);
    hws[frag * 512 + li * 8 + (k & 7)] = hv;
}

// ---------------------------------------------------------------------------
// Kernel 2: logits[m][n] = sum_k h[m][k]*W[n][k] + b_out[n].  M=256 N=32000
// K=256.  FREE-RUNNING WAVES, one barrier, no W-LDS, no K-loop.
//
// 250 blocks x 512 thr (8 waves), LDS = 128 KB h only (1 block/CU).
// Wave = 16 n-rows x all 256 m:
//   1. issue 16 global dwordx4: the wave's full W stripe DIRECT TO REGS.
//      Lanes l15 = 16 rows, lq = 4 x 32B chunks -> each instruction is 16
//      fully-contiguous 128B lines: perfectly coalesced, no LDS needed.
//   2. issue bias + 16 global_load_lds staging this wave's 16 KB h slice
//      (linear, frag-major).  W first = HBM long pole starts at t~0.
//   3. vmcnt(17 outstanding -> wait 16 oldest) via data-dep, cvt W->bf16.
//   4. vmcnt(0) + s_barrier (the ONLY barrier: h written by all waves).
//   5. 8 m-phases: {16 conflict-free ds_read_b128 B-frags, 16 MFMA,
//      2 f32x4 stores}.  Waves never sync again; stores spread over the
//      compute tail and overlap other CUs' loads chip-wide.
// W read from HBM exactly once (33 MB); writes 33 MB; h from L2.
// ---------------------------------------------------------------------------
__global__ __launch_bounds__(512, 2)
void logits_gemm(const unsigned short* __restrict__ hws,
                 const float* __restrict__ Ww,
                 const float* __restrict__ b_out,
                 float* __restrict__ out) {
    __shared__ unsigned short Hs[B_SZ * HID];   // 128 KB frag-major h

    const int t    = threadIdx.x;
    const int wid  = t >> 6;
    const int lane = t & 63;
    const int l15  = lane & 15;
    const int lq   = lane >> 4;

    const int n0w = blockIdx.x * 128 + wid * 16;   // wave's 16-row n stripe

    // ---- 1. W stripe direct to registers (16 x dwordx4, issued first) ----
    const float* wrow = Ww + (size_t)(n0w + l15) * HID + lq * 8;
    f32x4 wf[16];
    #pragma unroll
    for (int ks = 0; ks < 8; ++ks) {
        wf[2 * ks]     = *reinterpret_cast<const f32x4*>(wrow + ks * 32);
        wf[2 * ks + 1] = *reinterpret_cast<const f32x4*>(wrow + ks * 32 + 4);
    }
    __builtin_amdgcn_sched_barrier(0);   // pin issue order: W before bias/h

    // ---- 2. bias + h staging (linear gload_lds, R7-proven) ----
    f32x4 bv = *reinterpret_cast<const f32x4*>(b_out + n0w + lq * 4);
    #pragma unroll
    for (int j = 0; j < 16; ++j) {
        const unsigned short* src = hws + (wid * 16 + j) * 512 + lane * 8;
        __builtin_amdgcn_global_load_lds(
            (const __attribute__((address_space(1))) unsigned int*)src,
            (__attribute__((address_space(3))) unsigned int*)(Hs + (wid * 16 + j) * 512),
            16, 0, 0);
    }
    __builtin_amdgcn_sched_barrier(0);

    // ---- 3. cvt W -> bf16 A-frags (data-dep waits W; h still in flight) ----
    short8 aw[8];
    #pragma unroll
    for (int ks = 0; ks < 8; ++ks) {
        union { short8 s; unsigned u[4]; } p;
        p.u[0] = pkhi(wf[2 * ks][0],     wf[2 * ks][1]);
        p.u[1] = pkhi(wf[2 * ks][2],     wf[2 * ks][3]);
        p.u[2] = pkhi(wf[2 * ks + 1][0], wf[2 * ks + 1][1]);
        p.u[3] = pkhi(wf[2 * ks + 1][2], wf[2 * ks + 1][3]);
        aw[ks] = p.s;
    }

    // ---- 4. the only barrier: h landed in LDS ----
    asm volatile("s_waitcnt vmcnt(0)" ::: "memory");
    __builtin_amdgcn_s_barrier();
    __builtin_amdgcn_sched_barrier(0);

    // ---- 5. 8 m-phases, free-running ----
    const unsigned short* hb = Hs + lane * 8;
    #pragma unroll
    for (int p = 0; p < 8; ++p) {
        f32x4 acc[2] = {};
        #pragma unroll
        for (int ks = 0; ks < 8; ++ks)
            #pragma unroll
            for (int mf = 0; mf < 2; ++mf) {
                short8 bh = *reinterpret_cast<const short8*>(
                    hb + ((p * 2 + mf) * 8 + ks) * 512);
                acc[mf] = __builtin_amdgcn_mfma_f32_16x16x32_bf16(
                    aw[ks], bh, acc[mf], 0, 0, 0);
            }
        #pragma unroll
        for (int mf = 0; mf < 2; ++mf) {
            f32x4 o = acc[mf] + bv;
            *reinterpret_cast<f32x4*>(
                out + (size_t)(p * 32 + mf * 16 + l15) * NCLS + n0w + lq * 4) = o;
        }
    }
}

// ---------------------------------------------------------------------------
extern "C" void kernel_launch(void* const* d_in, const int* in_sizes, int n_in,
                              void* d_out, int out_size, void* d_ws, size_t ws_size,
                              hipStream_t stream) {
    const int*   X       = (const int*)  d_in[0];
    const float* C_table = (const float*)d_in[1];
    const float* U_i     = (const float*)d_in[2];
    const float* b_i     = (const float*)d_in[4];
    const float* U_c     = (const float*)d_in[8];
    const float* b_c     = (const float*)d_in[10];
    const float* U_o     = (const float*)d_in[11];
    const float* b_o     = (const float*)d_in[13];
    const float* W_w     = (const float*)d_in[26];
    const float* b_out   = (const float*)d_in[27];
    float* out = (float*)d_out;

    unsigned short* hws = (unsigned short*)d_ws;  // bf16 h_last, frag-major

    lstm_h_last<<<B_SZ, 256, 0, stream>>>(X, C_table, U_i, b_i, U_c, b_c,
                                          U_o, b_o, hws);
    logits_gemm<<<NCLS / 128, 512, 0, stream>>>(hws, W_w, b_out, out);
}